// Round 11
// baseline (443.571 us; speedup 1.0000x reference)
//
#include <hip/hip_runtime.h>
#include <stdint.h>

// ---------------------------------------------------------------------------
// MD5Surrogate: 64-round scan of 3-layer MLP (22->256->256->16), B=16384.
// fp32 in/out. R21 = R20 (fp16 datapath, 375us kernel) + LDS/latency fixes:
//  (1) SXW 32->40: R20's 64B x-row stride mapped 64 lanes to 2 LDS banks
//      (conflicts 2.73e7 -> 3.16e7); 80B stride (20 dwords) spreads 8 banks,
//      stays 16B-aligned for the b128 x reads.
//  (2) SM 66->68 (136B rows, 8B-aligned) + vectorized word scatter:
//      b64 read + b64 write + b32 write replaces 4 u16 reads + 6 u16 writes
//      on the critical D phase.
//  (3) Cross-barrier prefetch of the tt=0 a2 half (a2c[8], 16 VGPR, uniform
//      on all waves like a1c -- no conditional cross-barrier liveness, the
//      R13 spill rule): L2's first 16 MFMAs no longer eat ~300cy VMEM
//      latency; tt=1 a2 loads issue at L2 top and hide under Bf ds_reads.
// From R20: fp16 weights/x/h (single x, no hi/lo), packed-half2 gelu tail
// (t,e fp32 trans), h stored via pkrtz, mfma_f32_16x16x32_f16.
// From R17: 512thr/8w/NG=2/TT=2, 2 blocks/CU, distributed L3 (SIMD-parity
// pair, contained live ranges), cross-barrier a1/bb1/bb2 prefetch,
// bias-in-accumulator, 3 barriers/round.
// Ladders closed: occupancy (R11/R15/R16), LDS-table gelu (R18).
// ---------------------------------------------------------------------------

using f16x8    = __attribute__((ext_vector_type(8))) _Float16;
using f16x2    = __attribute__((ext_vector_type(2))) _Float16;
using fp16x2r  = __attribute__((ext_vector_type(2))) __fp16;  // builtin ret type
using floatx4  = __attribute__((ext_vector_type(4))) float;
using ushort4v = __attribute__((ext_vector_type(4))) unsigned short;
using uint2v   = __attribute__((ext_vector_type(2))) unsigned int;

__constant__ int c_sched[64] = {
  0,1,2,3,4,5,6,7,8,9,10,11,12,13,14,15,
  1,6,11,0,5,10,15,4,9,14,3,8,13,2,7,12,
  5,8,11,14,1,4,7,10,13,0,3,6,9,12,15,2,
  0,7,14,5,12,3,10,1,8,15,6,13,4,11,2,9
};
__constant__ float c_shift[64] = {
  7,12,17,22,7,12,17,22,7,12,17,22,7,12,17,22,
  5,9,14,20,5,9,14,20,5,9,14,20,5,9,14,20,
  4,11,16,23,4,11,16,23,4,11,16,23,4,11,16,23,
  6,10,15,21,6,10,15,21,6,10,15,21,6,10,15,21
};

__device__ __forceinline__ unsigned short f16bits(float x) {
  union { _Float16 h; unsigned short u; } v; v.h = (_Float16)x; return v.u;
}
__device__ __forceinline__ f16x2 pkrtz(float a, float b) {
  union { fp16x2r r; f16x2 h; } v; v.r = __builtin_amdgcn_cvt_pkrtz(a, b);
  return v.h;
}
#define H2(c) ((f16x2){(_Float16)(c), (_Float16)(c)})

// gelu on a PAIR of fp32 inputs -> packed fp16 pair (u32).
// A&S 7.1.25 (|eps|<=2.5e-5 in fp32; fp16 tail adds ~5e-4 abs worst-case).
__device__ __forceinline__ unsigned int gelu2(float a0, float a1) {
  float t0 = __builtin_amdgcn_rcpf(__builtin_fmaf(0.33270222f, fabsf(a0), 1.0f));
  float t1 = __builtin_amdgcn_rcpf(__builtin_fmaf(0.33270222f, fabsf(a1), 1.0f));
  float e0 = __builtin_amdgcn_exp2f(a0 * a0 * -0.72134752f);
  float e1 = __builtin_amdgcn_exp2f(a1 * a1 * -0.72134752f);
  f16x2 xp = pkrtz(a0, a1);
  f16x2 tp = pkrtz(t0, t1);
  f16x2 ep = pkrtz(e0, e1);
  f16x2 poly = tp * __builtin_elementwise_fma(
                   tp, __builtin_elementwise_fma(tp, H2(0.7478556f), H2(-0.0958798f)),
                   H2(0.3480242f));
  f16x2 er = __builtin_elementwise_fma(poly, -ep, H2(1.0f));
  union { f16x2 h; unsigned int u; } ue, ux, uo;
  ue.h = er; ux.h = xp;
  uo.u = (ue.u & 0x7FFF7FFFu) | (ux.u & 0x80008000u);   // copysign(er, x)
  f16x2 hx = xp * H2(0.5f);
  union { f16x2 h; unsigned int u; } r;
  r.h = __builtin_elementwise_fma(hx, uo.h, hx);        // 0.5x(1+er)
  return r.u;
}
__device__ __forceinline__ floatx4 mfma16f(f16x8 a, f16x8 b, floatx4 c) {
  return __builtin_amdgcn_mfma_f32_16x16x32_f16(a, b, c, 0, 0, 0);
}

// ---------------------------------------------------------------------------
// Packed-weight layout (fp16): fragment = 64 lanes x 8 fp16. A[m][k]:
// m=lane&15, k=8*(lane>>4)+j.  P1 (r*16+t): W1[r][k][16t+m] (k>=22 -> 0)
//                   P2 ((r*16+t)*8+c): W2[r][32c+k'][16t+m]
//                   P3 (r*8+c): W3[r][32c+k'][m]
// ---------------------------------------------------------------------------
#define N1G (64*16*64)
#define N2G (64*16*8*64)
#define N3G (64*8*64)

__global__ void pack_w(const float* __restrict__ W1,
                       const float* __restrict__ W2,
                       const float* __restrict__ W3,
                       unsigned short* __restrict__ P) {
  int gid = blockIdx.x * blockDim.x + threadIdx.x;
  if (gid >= N1G + N2G + N3G) return;
  unsigned short v[8];
  unsigned short* dst;
  if (gid < N1G) {
    int lane = gid & 63, t = (gid >> 6) & 15, r = gid >> 10;
    int qq = lane >> 4, mm = lane & 15;
    #pragma unroll
    for (int j = 0; j < 8; ++j) {
      int k = 8*qq + j;
      v[j] = (k < 22) ? f16bits(W1[(r*22 + k)*256 + 16*t + mm]) : (unsigned short)0;
    }
    dst = P + (size_t)gid * 8;
  } else if (gid < N1G + N2G) {
    int g = gid - N1G;
    int lane = g & 63, c = (g >> 6) & 7, t = (g >> 9) & 15, r = g >> 13;
    int qq = lane >> 4, mm = lane & 15;
    #pragma unroll
    for (int j = 0; j < 8; ++j) {
      int k = 32*c + 8*qq + j;
      v[j] = f16bits(W2[((size_t)r*256 + k)*256 + 16*t + mm]);
    }
    dst = P + (size_t)(N1G + g) * 8;
  } else {
    int g = gid - N1G - N2G;
    int lane = g & 63, c = (g >> 6) & 7, r = g >> 9;
    int qq = lane >> 4, mm = lane & 15;
    #pragma unroll
    for (int j = 0; j < 8; ++j) {
      int k = 32*c + 8*qq + j;
      v[j] = f16bits(W3[(r*256 + k)*16 + mm]);
    }
    dst = P + (size_t)(N1G + N2G + g) * 8;
  }
  ushort4v lo = { v[0],v[1],v[2],v[3] }, hi = { v[4],v[5],v[6],v[7] };
  *(ushort4v*)dst = lo;
  *(ushort4v*)(dst + 4) = hi;
}

// ---------------------------------------------------------------------------
#define NG  2    // row-groups per block (32 rows/block)
#define TT  2    // feature sub-tiles per wave (8 waves x 32 features = 256)
#define SXW 40   // x row stride (fp16): 22 real + zero pad; 80B = 8-bank spread
#define SH 264   // h row stride
#define SM 68    // msg row stride (136B rows -> 8B-aligned b64 word reads)

__global__ __launch_bounds__(512, 4) void md5_main(
    const float* __restrict__ msg,   // (16384,64)
    const float* __restrict__ st0,   // (16384,16)
    const float* __restrict__ b1,    // (64,256)
    const float* __restrict__ b2,    // (64,256)
    const float* __restrict__ b3,    // (64,16)
    const unsigned short* __restrict__ P,
    float* __restrict__ out)         // (16384,16)
{
  __shared__ __align__(16) unsigned short xh[NG][16][SXW];
  __shared__ __align__(16) unsigned short hA[NG][16][SH], hB[NG][16][SH];
  __shared__ __align__(16) unsigned short msgb[NG*16][SM];

  const int tid  = threadIdx.x;
  const int wv   = tid >> 6;        // 0..7
  const int lane = tid & 63;
  const int q    = lane >> 4;
  const int ln   = lane & 15;
  const int row0 = blockIdx.x * (NG*16);
  const int l3w  = (blockIdx.x & 1) << 1;   // L3 waves {l3w, l3w+1}
  const int scw  = l3w ^ 2;                 // scatter wave on the other SIMD pair

  const unsigned short* P1 = P;
  const unsigned short* P2 = P + (size_t)N1G * 8;
  const unsigned short* P3 = P + (size_t)(N1G + N2G) * 8;

  // zero x buffer once (pad cols 22..39 must stay 0 forever)
  for (int i = tid; i < NG*16*SXW; i += 512) (&xh[0][0][0])[i] = 0;
  // msg preload (fp16): 32 rows x 64 = 2048 elems / 512 thr = 4 each
  {
    int idx = tid * 4, rr = idx >> 6, cc = idx & 63;
    floatx4 v0 = *(const floatx4*)(msg + (size_t)(row0 + rr)*64 + cc);
    #pragma unroll
    for (int j = 0; j < 4; ++j) msgb[rr][cc + j] = f16bits(v0[j]);
  }
  // init state (fp16, RTE): one wave suffices (ordered by barrier below)
  if (wv == 0) {
    #pragma unroll
    for (int g = 0; g < NG; ++g) {
      floatx4 v = *(const floatx4*)(st0 + (size_t)(row0 + g*16 + ln)*16 + 4*q);
      ushort4v h4;
      #pragma unroll
      for (int e = 0; e < 4; ++e) h4[e] = f16bits(v[e]);
      *(ushort4v*)&xh[g][ln][4*q] = h4;
    }
  }
  __syncthreads();   // msgb + state + zero-pads ready
  // round-0 word+rinfo: every wave writes the full identical set (benign race)
  if (lane < NG*16) {
    int g = lane >> 4, n = lane & 15, rrow = lane;
    int s = c_sched[0];
    uint2v w4 = *(const uint2v*)&msgb[rrow][4*s];
    *(uint2v*)&xh[g][n][16] = w4;
    *(unsigned int*)&xh[g][n][20] =
        (unsigned int)f16bits(c_shift[0] / 25.0f) << 16;   // i0 = 0
  }

  // ---- prefetched regs for round r: a1/bb1 (L1), bb2 + tt=0 a2 half (L2) --
  f16x8   a1c[TT], a2c[8];  floatx4 bb1c[TT], bb2c[TT];
  {
    const unsigned short* p1 = P1 + ((size_t)(TT*wv)*64 + lane)*8;
    #pragma unroll
    for (int tt = 0; tt < TT; ++tt) {
      a1c[tt]  = *(const f16x8*)(p1 + (size_t)tt*512);
      bb1c[tt] = *(const floatx4*)(b1 + (TT*wv + tt)*16 + 4*q);
      bb2c[tt] = *(const floatx4*)(b2 + (TT*wv + tt)*16 + 4*q);
    }
    const unsigned short* p2 = P2 + ((size_t)((TT*wv)*8)*64 + lane)*8;
    #pragma unroll
    for (int c = 0; c < 8; ++c) a2c[c] = *(const f16x8*)(p2 + (size_t)c*512);
  }

  #pragma unroll 1
  for (int r = 0; r < 64; ++r) {
    // -------- Layer 1: x @ W1 -> h1 (own 32-feature slice, both groups) ----
    f16x8 bx[NG];
    #pragma unroll
    for (int g = 0; g < NG; ++g) bx[g] = *(const f16x8*)&xh[g][ln][8*q];
    #pragma unroll
    for (int tt = 0; tt < TT; ++tt) {
      int f0 = (TT*wv + tt)*16 + 4*q;
      #pragma unroll
      for (int g = 0; g < NG; ++g) {
        floatx4 acc = mfma16f(a1c[tt], bx[g], bb1c[tt]);
        uint2v w = { gelu2(acc[0], acc[1]), gelu2(acc[2], acc[3]) };
        *(uint2v*)&hA[g][ln][f0] = w;
      }
    }
    __syncthreads();                       // (B) h1 ready; hB free

    // -------- Layer 2: h1 @ W2 -> h2 (own slice, both groups) --------
    // tt=1 a2 loads issue first (latency hides under the Bf ds_reads);
    // tt=0 half was prefetched across barrier C last round.
    f16x8 a2b[8];
    {
      const unsigned short* p2 = P2 + ((size_t)((r*16 + TT*wv)*8)*64 + lane)*8;
      #pragma unroll
      for (int c = 0; c < 8; ++c)
        a2b[c] = *(const f16x8*)(p2 + (size_t)(8 + c)*512);
    }
    f16x8 Bf[NG][8];
    #pragma unroll
    for (int g = 0; g < NG; ++g)
      #pragma unroll
      for (int c = 0; c < 8; ++c) Bf[g][c] = *(const f16x8*)&hA[g][ln][32*c + 8*q];

    #pragma unroll
    for (int tt = 0; tt < TT; ++tt) {
      int f0 = (TT*wv + tt)*16 + 4*q;
      #pragma unroll
      for (int g = 0; g < NG; ++g) {
        floatx4 acc = bb2c[tt];
        #pragma unroll
        for (int c = 0; c < 8; ++c)
          acc = mfma16f(tt == 0 ? a2c[c] : a2b[c], Bf[g][c], acc);
        uint2v w = { gelu2(acc[0], acc[1]), gelu2(acc[2], acc[3]) };
        *(uint2v*)&hB[g][ln][f0] = w;
      }
    }
    __syncthreads();                       // (C) h2 ready

    // -------- prefetch next round's a1/bb1/bb2 + tt=0 a2 half --------------
    if (r < 63) {
      const unsigned short* p1n = P1 + ((size_t)((r+1)*16 + TT*wv)*64 + lane)*8;
      #pragma unroll
      for (int tt = 0; tt < TT; ++tt) {
        a1c[tt]  = *(const f16x8*)(p1n + (size_t)tt*512);
        bb1c[tt] = *(const floatx4*)(b1 + (r+1)*256 + (TT*wv + tt)*16 + 4*q);
        bb2c[tt] = *(const floatx4*)(b2 + (r+1)*256 + (TT*wv + tt)*16 + 4*q);
      }
      const unsigned short* p2n = P2 + ((size_t)(((r+1)*16 + TT*wv)*8)*64 + lane)*8;
      #pragma unroll
      for (int c = 0; c < 8; ++c) a2c[c] = *(const f16x8*)(p2n + (size_t)c*512);
    }

    // -------- Layer 3 (distributed; SIMD-parity-balanced wave pair) --------
    // a3/bb3 loaded inside the branch: contained live range, no spill.
    if (wv == l3w || wv == l3w + 1) {
      const int g = wv - l3w;
      const unsigned short* p3 = P3 + ((size_t)(r*8)*64 + lane)*8;
      f16x8 a3[8];
      #pragma unroll
      for (int c = 0; c < 8; ++c) a3[c] = *(const f16x8*)(p3 + (size_t)c*512);
      floatx4 s = *(const floatx4*)(b3 + r*16 + 4*q);
      #pragma unroll
      for (int c = 0; c < 8; ++c) {
        f16x8 bh = *(const f16x8*)&hB[g][ln][32*c + 8*q];
        s = mfma16f(a3[c], bh, s);
      }
      if (r == 63) {
        *(floatx4*)(out + (size_t)(row0 + g*16 + ln)*16 + 4*q) = s;
      } else {
        // state write: RTE scalar casts (64-round chain sensitivity)
        ushort4v h4;
        #pragma unroll
        for (int e = 0; e < 4; ++e) h4[e] = f16bits(s[e]);
        *(ushort4v*)&xh[g][ln][4*q] = h4;
      }
    }
    // word + rinfo for next round: scatter wave (other SIMD pair), vectorized
    if (wv == scw && lane < NG*16 && r < 63) {
      int g = lane >> 4, n = lane & 15, rrow = lane;
      int sc = c_sched[r+1];
      uint2v w4 = *(const uint2v*)&msgb[rrow][4*sc];
      *(uint2v*)&xh[g][n][16] = w4;
      float i0 = (float)(r+1) * 0.015625f;   // exact in fp16
      *(unsigned int*)&xh[g][n][20] =
          (unsigned int)f16bits(i0) | ((unsigned int)f16bits(c_shift[r+1] / 25.0f) << 16);
    }
    if (r < 63) __syncthreads();           // (D) x ready for next L1
  }
}

// ---------------------------------------------------------------------------
extern "C" void kernel_launch(void* const* d_in, const int* in_sizes, int n_in,
                              void* d_out, int out_size, void* d_ws, size_t ws_size,
                              hipStream_t stream) {
  const float* msg = (const float*)d_in[0];
  const float* st0 = (const float*)d_in[1];
  const float* W1  = (const float*)d_in[2];
  const float* b1  = (const float*)d_in[3];
  const float* W2  = (const float*)d_in[4];
  const float* b2  = (const float*)d_in[5];
  const float* W3  = (const float*)d_in[6];
  const float* b3  = (const float*)d_in[7];
  float* out = (float*)d_out;
  (void)in_sizes; (void)n_in; (void)out_size; (void)ws_size;

  unsigned short* P = (unsigned short*)d_ws;
  const int totalGroups = N1G + N2G + N3G;   // 622592
  pack_w<<<(totalGroups + 255) / 256, 256, 0, stream>>>(W1, W2, W3, P);
  md5_main<<<512, 512, 0, stream>>>(msg, st0, b1, b2, b3, P, out);
}

// Round 12
// 407.930 us; speedup vs baseline: 1.0874x; 1.0874x over previous
//
#include <hip/hip_runtime.h>
#include <stdint.h>

// ---------------------------------------------------------------------------
// MD5Surrogate: 64-round scan of 3-layer MLP (22->256->256->16), B=16384.
// fp32 in/out. R22 = R20 (fp16 datapath, 375us best) + ONLY the two LDS
// layout fixes from R21 (its a2c cross-barrier prefetch is reverted: vmcnt
// is in-order, so the L3 waves' 18 prefetch loads queued AHEAD of their
// critical-path a3 loads -- plus a small spill (WRITE_SIZE 1->4MB). Net -26us).
//  (1) SXW 32->40: R20's 64B x-row stride mapped the 16 x-rows to 2 LDS
//      banks; 80B stride = 2-way max (free per m136), 16B-aligned b128 reads.
//  (2) SM 66->68 (136B rows) + vectorized word scatter on phase D:
//      b64 read + b64 write + b32 write replaces 4 u16 reads + 6 u16 writes.
// From R20: fp16 weights/x/h (single x, no hi/lo split), packed-half2 gelu
// tail (t,e fp32 trans), h stored via pkrtz pack, mfma_f32_16x16x32_f16,
// a2 loaded per-tt in-loop (compiler schedules), state writes RTE.
// From R17: 512thr/8w/NG=2/TT=2, 2 blocks/CU, distributed L3 (SIMD-parity
// pair, a3/bb3 live range contained inside branch -> no spill), word scatter
// on own wave, cross-barrier a1/bb1/bb2 prefetch (10 loads -- proven net
// positive in R17; 18 proven negative in R21), bias-in-accumulator,
// 3 barriers/round.
// Ladders closed: occupancy (R11/R15/R16), LDS-table gelu (R18), deep
// cross-barrier prefetch (R21).
// ---------------------------------------------------------------------------

using f16x8    = __attribute__((ext_vector_type(8))) _Float16;
using f16x2    = __attribute__((ext_vector_type(2))) _Float16;
using fp16x2r  = __attribute__((ext_vector_type(2))) __fp16;  // builtin ret type
using floatx4  = __attribute__((ext_vector_type(4))) float;
using ushort4v = __attribute__((ext_vector_type(4))) unsigned short;
using uint2v   = __attribute__((ext_vector_type(2))) unsigned int;

__constant__ int c_sched[64] = {
  0,1,2,3,4,5,6,7,8,9,10,11,12,13,14,15,
  1,6,11,0,5,10,15,4,9,14,3,8,13,2,7,12,
  5,8,11,14,1,4,7,10,13,0,3,6,9,12,15,2,
  0,7,14,5,12,3,10,1,8,15,6,13,4,11,2,9
};
__constant__ float c_shift[64] = {
  7,12,17,22,7,12,17,22,7,12,17,22,7,12,17,22,
  5,9,14,20,5,9,14,20,5,9,14,20,5,9,14,20,
  4,11,16,23,4,11,16,23,4,11,16,23,4,11,16,23,
  6,10,15,21,6,10,15,21,6,10,15,21,6,10,15,21
};

__device__ __forceinline__ unsigned short f16bits(float x) {
  union { _Float16 h; unsigned short u; } v; v.h = (_Float16)x; return v.u;
}
__device__ __forceinline__ f16x2 pkrtz(float a, float b) {
  union { fp16x2r r; f16x2 h; } v; v.r = __builtin_amdgcn_cvt_pkrtz(a, b);
  return v.h;
}
#define H2(c) ((f16x2){(_Float16)(c), (_Float16)(c)})

// gelu on a PAIR of fp32 inputs -> packed fp16 pair (u32).
// A&S 7.1.25 (|eps|<=2.5e-5 in fp32; fp16 tail adds ~5e-4 abs worst-case).
__device__ __forceinline__ unsigned int gelu2(float a0, float a1) {
  float t0 = __builtin_amdgcn_rcpf(__builtin_fmaf(0.33270222f, fabsf(a0), 1.0f));
  float t1 = __builtin_amdgcn_rcpf(__builtin_fmaf(0.33270222f, fabsf(a1), 1.0f));
  float e0 = __builtin_amdgcn_exp2f(a0 * a0 * -0.72134752f);
  float e1 = __builtin_amdgcn_exp2f(a1 * a1 * -0.72134752f);
  f16x2 xp = pkrtz(a0, a1);
  f16x2 tp = pkrtz(t0, t1);
  f16x2 ep = pkrtz(e0, e1);
  f16x2 poly = tp * __builtin_elementwise_fma(
                   tp, __builtin_elementwise_fma(tp, H2(0.7478556f), H2(-0.0958798f)),
                   H2(0.3480242f));
  f16x2 er = __builtin_elementwise_fma(poly, -ep, H2(1.0f));
  union { f16x2 h; unsigned int u; } ue, ux, uo;
  ue.h = er; ux.h = xp;
  uo.u = (ue.u & 0x7FFF7FFFu) | (ux.u & 0x80008000u);   // copysign(er, x)
  f16x2 hx = xp * H2(0.5f);
  union { f16x2 h; unsigned int u; } r;
  r.h = __builtin_elementwise_fma(hx, uo.h, hx);        // 0.5x(1+er)
  return r.u;
}
__device__ __forceinline__ floatx4 mfma16f(f16x8 a, f16x8 b, floatx4 c) {
  return __builtin_amdgcn_mfma_f32_16x16x32_f16(a, b, c, 0, 0, 0);
}

// ---------------------------------------------------------------------------
// Packed-weight layout (fp16): fragment = 64 lanes x 8 fp16. A[m][k]:
// m=lane&15, k=8*(lane>>4)+j.  P1 (r*16+t): W1[r][k][16t+m] (k>=22 -> 0)
//                   P2 ((r*16+t)*8+c): W2[r][32c+k'][16t+m]
//                   P3 (r*8+c): W3[r][32c+k'][m]
// ---------------------------------------------------------------------------
#define N1G (64*16*64)
#define N2G (64*16*8*64)
#define N3G (64*8*64)

__global__ void pack_w(const float* __restrict__ W1,
                       const float* __restrict__ W2,
                       const float* __restrict__ W3,
                       unsigned short* __restrict__ P) {
  int gid = blockIdx.x * blockDim.x + threadIdx.x;
  if (gid >= N1G + N2G + N3G) return;
  unsigned short v[8];
  unsigned short* dst;
  if (gid < N1G) {
    int lane = gid & 63, t = (gid >> 6) & 15, r = gid >> 10;
    int qq = lane >> 4, mm = lane & 15;
    #pragma unroll
    for (int j = 0; j < 8; ++j) {
      int k = 8*qq + j;
      v[j] = (k < 22) ? f16bits(W1[(r*22 + k)*256 + 16*t + mm]) : (unsigned short)0;
    }
    dst = P + (size_t)gid * 8;
  } else if (gid < N1G + N2G) {
    int g = gid - N1G;
    int lane = g & 63, c = (g >> 6) & 7, t = (g >> 9) & 15, r = g >> 13;
    int qq = lane >> 4, mm = lane & 15;
    #pragma unroll
    for (int j = 0; j < 8; ++j) {
      int k = 32*c + 8*qq + j;
      v[j] = f16bits(W2[((size_t)r*256 + k)*256 + 16*t + mm]);
    }
    dst = P + (size_t)(N1G + g) * 8;
  } else {
    int g = gid - N1G - N2G;
    int lane = g & 63, c = (g >> 6) & 7, r = g >> 9;
    int qq = lane >> 4, mm = lane & 15;
    #pragma unroll
    for (int j = 0; j < 8; ++j) {
      int k = 32*c + 8*qq + j;
      v[j] = f16bits(W3[(r*256 + k)*16 + mm]);
    }
    dst = P + (size_t)(N1G + N2G + g) * 8;
  }
  ushort4v lo = { v[0],v[1],v[2],v[3] }, hi = { v[4],v[5],v[6],v[7] };
  *(ushort4v*)dst = lo;
  *(ushort4v*)(dst + 4) = hi;
}

// ---------------------------------------------------------------------------
#define NG  2    // row-groups per block (32 rows/block)
#define TT  2    // feature sub-tiles per wave (8 waves x 32 features = 256)
#define SXW 40   // x row stride (fp16): 80B = 2-way max bank aliasing
#define SH 264   // h row stride
#define SM 68    // msg row stride (136B rows -> 8B-aligned b64 word reads)

__global__ __launch_bounds__(512, 4) void md5_main(
    const float* __restrict__ msg,   // (16384,64)
    const float* __restrict__ st0,   // (16384,16)
    const float* __restrict__ b1,    // (64,256)
    const float* __restrict__ b2,    // (64,256)
    const float* __restrict__ b3,    // (64,16)
    const unsigned short* __restrict__ P,
    float* __restrict__ out)         // (16384,16)
{
  __shared__ __align__(16) unsigned short xh[NG][16][SXW];
  __shared__ __align__(16) unsigned short hA[NG][16][SH], hB[NG][16][SH];
  __shared__ __align__(16) unsigned short msgb[NG*16][SM];

  const int tid  = threadIdx.x;
  const int wv   = tid >> 6;        // 0..7
  const int lane = tid & 63;
  const int q    = lane >> 4;
  const int ln   = lane & 15;
  const int row0 = blockIdx.x * (NG*16);
  const int l3w  = (blockIdx.x & 1) << 1;   // L3 waves {l3w, l3w+1}
  const int scw  = l3w ^ 2;                 // scatter wave on the other SIMD pair

  const unsigned short* P1 = P;
  const unsigned short* P2 = P + (size_t)N1G * 8;
  const unsigned short* P3 = P + (size_t)(N1G + N2G) * 8;

  // zero x buffer once (pad cols 22..39 must stay 0 forever)
  for (int i = tid; i < NG*16*SXW; i += 512) (&xh[0][0][0])[i] = 0;
  // msg preload (fp16): 32 rows x 64 = 2048 elems / 512 thr = 4 each
  {
    int idx = tid * 4, rr = idx >> 6, cc = idx & 63;
    floatx4 v0 = *(const floatx4*)(msg + (size_t)(row0 + rr)*64 + cc);
    #pragma unroll
    for (int j = 0; j < 4; ++j) msgb[rr][cc + j] = f16bits(v0[j]);
  }
  // init state (fp16, RTE): one wave suffices (ordered by barrier below)
  if (wv == 0) {
    #pragma unroll
    for (int g = 0; g < NG; ++g) {
      floatx4 v = *(const floatx4*)(st0 + (size_t)(row0 + g*16 + ln)*16 + 4*q);
      ushort4v h4;
      #pragma unroll
      for (int e = 0; e < 4; ++e) h4[e] = f16bits(v[e]);
      *(ushort4v*)&xh[g][ln][4*q] = h4;
    }
  }
  __syncthreads();   // msgb + state + zero-pads ready
  // round-0 word+rinfo: every wave writes the full identical set (benign race)
  if (lane < NG*16) {
    int g = lane >> 4, n = lane & 15, rrow = lane;
    int s = c_sched[0];
    uint2v w4 = *(const uint2v*)&msgb[rrow][4*s];
    *(uint2v*)&xh[g][n][16] = w4;
    *(unsigned int*)&xh[g][n][20] =
        (unsigned int)f16bits(c_shift[0] / 25.0f) << 16;   // i0 = 0
  }

  // ---- prefetched regs for round r: a1/bb1 (L1) + bb2 (L2 acc init) ----
  f16x8   a1c[TT];  floatx4 bb1c[TT], bb2c[TT];
  {
    const unsigned short* p1 = P1 + ((size_t)(TT*wv)*64 + lane)*8;
    #pragma unroll
    for (int tt = 0; tt < TT; ++tt) {
      a1c[tt]  = *(const f16x8*)(p1 + (size_t)tt*512);
      bb1c[tt] = *(const floatx4*)(b1 + (TT*wv + tt)*16 + 4*q);
      bb2c[tt] = *(const floatx4*)(b2 + (TT*wv + tt)*16 + 4*q);
    }
  }

  #pragma unroll 1
  for (int r = 0; r < 64; ++r) {
    // -------- Layer 1: x @ W1 -> h1 (own 32-feature slice, both groups) ----
    f16x8 bx[NG];
    #pragma unroll
    for (int g = 0; g < NG; ++g) bx[g] = *(const f16x8*)&xh[g][ln][8*q];
    #pragma unroll
    for (int tt = 0; tt < TT; ++tt) {
      int f0 = (TT*wv + tt)*16 + 4*q;
      #pragma unroll
      for (int g = 0; g < NG; ++g) {
        floatx4 acc = mfma16f(a1c[tt], bx[g], bb1c[tt]);
        uint2v w = { gelu2(acc[0], acc[1]), gelu2(acc[2], acc[3]) };
        *(uint2v*)&hA[g][ln][f0] = w;
      }
    }
    __syncthreads();                       // (B) h1 ready; hB free

    // -------- Layer 2: h1 @ W2 -> h2 (own slice, both groups) --------
    f16x8 Bf[NG][8];
    #pragma unroll
    for (int g = 0; g < NG; ++g)
      #pragma unroll
      for (int c = 0; c < 8; ++c) Bf[g][c] = *(const f16x8*)&hA[g][ln][32*c + 8*q];

    const unsigned short* p2 = P2 + ((size_t)((r*16 + TT*wv)*8)*64 + lane)*8;
    #pragma unroll
    for (int tt = 0; tt < TT; ++tt) {
      f16x8 a2[8];
      #pragma unroll
      for (int c = 0; c < 8; ++c)
        a2[c] = *(const f16x8*)(p2 + (size_t)(tt*8 + c)*512);
      int f0 = (TT*wv + tt)*16 + 4*q;
      #pragma unroll
      for (int g = 0; g < NG; ++g) {
        floatx4 acc = bb2c[tt];
        #pragma unroll
        for (int c = 0; c < 8; ++c) acc = mfma16f(a2[c], Bf[g][c], acc);
        uint2v w = { gelu2(acc[0], acc[1]), gelu2(acc[2], acc[3]) };
        *(uint2v*)&hB[g][ln][f0] = w;
      }
    }
    __syncthreads();                       // (C) h2 ready

    // -------- prefetch next round's a1/bb1/bb2 (hides under L3 + barrier D)
    if (r < 63) {
      const unsigned short* p1n = P1 + ((size_t)((r+1)*16 + TT*wv)*64 + lane)*8;
      #pragma unroll
      for (int tt = 0; tt < TT; ++tt) {
        a1c[tt]  = *(const f16x8*)(p1n + (size_t)tt*512);
        bb1c[tt] = *(const floatx4*)(b1 + (r+1)*256 + (TT*wv + tt)*16 + 4*q);
        bb2c[tt] = *(const floatx4*)(b2 + (r+1)*256 + (TT*wv + tt)*16 + 4*q);
      }
    }

    // -------- Layer 3 (distributed; SIMD-parity-balanced wave pair) --------
    // a3/bb3 loaded inside the branch: contained live range, no spill.
    if (wv == l3w || wv == l3w + 1) {
      const int g = wv - l3w;
      const unsigned short* p3 = P3 + ((size_t)(r*8)*64 + lane)*8;
      f16x8 a3[8];
      #pragma unroll
      for (int c = 0; c < 8; ++c) a3[c] = *(const f16x8*)(p3 + (size_t)c*512);
      floatx4 s = *(const floatx4*)(b3 + r*16 + 4*q);
      #pragma unroll
      for (int c = 0; c < 8; ++c) {
        f16x8 bh = *(const f16x8*)&hB[g][ln][32*c + 8*q];
        s = mfma16f(a3[c], bh, s);
      }
      if (r == 63) {
        *(floatx4*)(out + (size_t)(row0 + g*16 + ln)*16 + 4*q) = s;
      } else {
        // state write: RTE scalar casts (64-round chain sensitivity)
        ushort4v h4;
        #pragma unroll
        for (int e = 0; e < 4; ++e) h4[e] = f16bits(s[e]);
        *(ushort4v*)&xh[g][ln][4*q] = h4;
      }
    }
    // word + rinfo for next round: scatter wave (other SIMD pair), vectorized
    if (wv == scw && lane < NG*16 && r < 63) {
      int g = lane >> 4, n = lane & 15, rrow = lane;
      int sc = c_sched[r+1];
      uint2v w4 = *(const uint2v*)&msgb[rrow][4*sc];
      *(uint2v*)&xh[g][n][16] = w4;
      float i0 = (float)(r+1) * 0.015625f;   // exact in fp16
      *(unsigned int*)&xh[g][n][20] =
          (unsigned int)f16bits(i0) | ((unsigned int)f16bits(c_shift[r+1] / 25.0f) << 16);
    }
    if (r < 63) __syncthreads();           // (D) x ready for next L1
  }
}

// ---------------------------------------------------------------------------
extern "C" void kernel_launch(void* const* d_in, const int* in_sizes, int n_in,
                              void* d_out, int out_size, void* d_ws, size_t ws_size,
                              hipStream_t stream) {
  const float* msg = (const float*)d_in[0];
  const float* st0 = (const float*)d_in[1];
  const float* W1  = (const float*)d_in[2];
  const float* b1  = (const float*)d_in[3];
  const float* W2  = (const float*)d_in[4];
  const float* b2  = (const float*)d_in[5];
  const float* W3  = (const float*)d_in[6];
  const float* b3  = (const float*)d_in[7];
  float* out = (float*)d_out;
  (void)in_sizes; (void)n_in; (void)out_size; (void)ws_size;

  unsigned short* P = (unsigned short*)d_ws;
  const int totalGroups = N1G + N2G + N3G;   // 622592
  pack_w<<<(totalGroups + 255) / 256, 256, 0, stream>>>(W1, W2, W3, P);
  md5_main<<<512, 512, 0, stream>>>(msg, st0, b1, b2, b3, P, out);
}